// Round 1
// baseline (2176.706 us; speedup 1.0000x reference)
//
#include <hip/hip_runtime.h>
#include <stdint.h>

static constexpr float kThresh = 0.3f;
static constexpr int N  = 2048;   // detections per batch (fixed by problem)
static constexpr int NT = 1024;   // threads per block
static constexpr int EPT = N / NT;   // elements per thread = 2
static constexpr int NW  = NT / 64;  // waves per block = 16

__launch_bounds__(NT, 1)
__global__ void soft_nms_kernel(const float* __restrict__ det,
                                float* __restrict__ out, int B) {
    const int b    = blockIdx.x;
    const int t    = threadIdx.x;
    const int lane = t & 63;
    const int wid  = t >> 6;

    // Boxes staged in LDS so the picked box is a broadcast read (no extra barrier).
    __shared__ float sx1[N], sy1[N], sx2[N], sy2[N], sar[N];
    // Double-buffered per-wave argmax slots: one barrier/iteration is race-free.
    __shared__ unsigned long long red[2][NW];

    const float* dbase = det + (size_t)b * N * 5;

    float s[EPT], fin[EPT];
    float x1[EPT], y1[EPT], x2[EPT], y2[EPT], ar[EPT];

    #pragma unroll
    for (int e = 0; e < EPT; ++e) {
        const int j = t + e * NT;
        const float* p = dbase + (size_t)j * 5;
        x1[e] = p[0]; y1[e] = p[1]; x2[e] = p[2]; y2[e] = p[3];
        const float sc = p[4];
        ar[e]  = (x2[e] - x1[e] + 1.0f) * (y2[e] - y1[e] + 1.0f);
        s[e]   = (sc > kThresh) ? sc : -1.0f;   // s<0 encodes "inactive"
        fin[e] = -1.0f;
        sx1[j] = x1[e]; sy1[j] = y1[e]; sx2[j] = x2[e]; sy2[j] = y2[e]; sar[j] = ar[e];
    }
    __syncthreads();

    for (int it = 0; it < N; ++it) {
        // --- build sortable key: (f32 bits of score) << 32 | (N - j) ---
        // score >= 0 => bit pattern is order-preserving; low field breaks ties
        // toward the LOWEST index (matches jnp.argmax); key==0 <=> inactive,
        // and an active score of exactly 0.0 still wins via the nonzero index.
        unsigned long long k = 0ULL;
        #pragma unroll
        for (int e = 0; e < EPT; ++e) {
            const int j = t + e * NT;
            if (s[e] >= 0.0f) {
                unsigned long long ke =
                    ((unsigned long long)__float_as_uint(s[e]) << 32) |
                    (unsigned)(N - j);
                if (ke > k) k = ke;
            }
        }
        // --- wave-level u64 max reduce ---
        #pragma unroll
        for (int off = 1; off < 64; off <<= 1) {
            unsigned long long o = __shfl_xor(k, off, 64);
            if (o > k) k = o;
        }
        if (lane == 0) red[it & 1][wid] = k;
        __syncthreads();
        // --- cross-wave max (broadcast reads, every thread computes it) ---
        unsigned long long best = red[it & 1][0];
        #pragma unroll
        for (int w = 1; w < NW; ++w) {
            unsigned long long o = red[it & 1][w];
            if (o > best) best = o;
        }
        if (best == 0ULL) break;   // no active detections left (exact: remaining
                                   // reference steps are provable no-ops)

        const int   i = N - (int)(best & 0xFFFFFFFFu);
        const float v = __uint_as_float((unsigned)(best >> 32));
        const float bx1 = sx1[i], by1 = sy1[i], bx2 = sx2[i], by2 = sy2[i];
        const float ba  = sar[i];

        #pragma unroll
        for (int e = 0; e < EPT; ++e) {
            const int j = t + e * NT;
            if (j == i) {
                fin[e] = v;        // record picked (decayed) score
                s[e]   = -1.0f;    // deactivate before decay, like the reference
            } else if (s[e] >= 0.0f) {
                const float xx1 = fmaxf(bx1, x1[e]);
                const float yy1 = fmaxf(by1, y1[e]);
                const float xx2 = fminf(bx2, x2[e]);
                const float yy2 = fminf(by2, y2[e]);
                const float ww  = fmaxf(xx2 - xx1 + 1.0f, 0.0f);
                const float hh  = fmaxf(yy2 - yy1 + 1.0f, 0.0f);
                const float inter = ww * hh;
                const float iou   = inter / (ba + ar[e] - inter);
                s[e] *= expf(-(iou * iou) * 2.0f);   // /SIGMA(=0.5) == *2 exactly
            }
        }
    }

    // --- outputs: final (B,N) f32 then keep (B,N) as 0/1 f32 ---
    float* of = out + (size_t)b * N;
    float* ok = out + (size_t)B * N + (size_t)b * N;
    #pragma unroll
    for (int e = 0; e < EPT; ++e) {
        const int j = t + e * NT;
        of[j] = fin[e];
        ok[j] = (fin[e] > kThresh) ? 1.0f : 0.0f;
    }
}

extern "C" void kernel_launch(void* const* d_in, const int* in_sizes, int n_in,
                              void* d_out, int out_size, void* d_ws, size_t ws_size,
                              hipStream_t stream) {
    const float* det = (const float*)d_in[0];
    float* out = (float*)d_out;
    const int B = in_sizes[0] / (N * 5);
    hipLaunchKernelGGL(soft_nms_kernel, dim3(B), dim3(NT), 0, stream, det, out, B);
}

// Round 2
// 1824.981 us; speedup vs baseline: 1.1927x; 1.1927x over previous
//
#include <hip/hip_runtime.h>
#include <stdint.h>

static constexpr float kThresh = 0.3f;
static constexpr int N   = 2048;     // detections per batch (fixed by problem)
static constexpr int NT  = 512;      // threads per block
static constexpr int EPT = N / NT;   // 4 elements per thread (contiguous)
static constexpr int NW  = NT / 64;  // 8 waves per block

// One DPP max step: fmax(v, lanes-moved v). bound_ctrl=false + old=v makes
// invalid-source lanes a no-op (fmax(v,v)). CDNA keeps gfx9 row_shr/row_bcast.
template <int CTRL>
__device__ __forceinline__ float dpp_fmax(float v) {
    int m = __builtin_amdgcn_update_dpp(__float_as_int(v), __float_as_int(v),
                                        CTRL, 0xF, 0xF, false);
    return fmaxf(v, __int_as_float(m));
}

__launch_bounds__(NT, 1)
__global__ void soft_nms_kernel(const float* __restrict__ det,
                                float* __restrict__ out, int B) {
    const int b    = blockIdx.x;
    const int t    = threadIdx.x;
    const int lane = t & 63;
    const int wid  = t >> 6;
    const int base = t * EPT;        // contiguous ownership: lane order == index order

    __shared__ float4 sbox[N];       // (x1,y1,x2,y2) -> one ds_read_b128 broadcast
    __shared__ float  sar[N];
    __shared__ unsigned long long redk[2][NW];   // double-buffered wave keys

    const float* dbase = det + (size_t)b * N * 5;

    float s[EPT], fin[EPT], x1[EPT], y1[EPT], x2[EPT], y2[EPT], ar[EPT];

    #pragma unroll
    for (int e = 0; e < EPT; ++e) {
        const int j = base + e;
        const float* p = dbase + (size_t)j * 5;
        x1[e] = p[0]; y1[e] = p[1]; x2[e] = p[2]; y2[e] = p[3];
        const float sc = p[4];
        ar[e]  = (x2[e] - x1[e] + 1.0f) * (y2[e] - y1[e] + 1.0f);
        s[e]   = (sc > kThresh) ? sc : -1.0f;    // s<0 encodes "inactive"
        fin[e] = -1.0f;
        sbox[j] = make_float4(x1[e], y1[e], x2[e], y2[e]);
        sar[j]  = ar[e];
    }
    __syncthreads();

    for (int it = 0; it < N; ++it) {
        // --- per-thread argmax over EPT (strict > keeps lowest index) ---
        float sb = s[0];
        int   bi = base;
        #pragma unroll
        for (int e = 1; e < EPT; ++e)
            if (s[e] > sb) { sb = s[e]; bi = base + e; }

        // --- wave max on f32 score via DPP (VALU-speed, no LDS pipe) ---
        float a = sb;
        a = dpp_fmax<0x111>(a);   // row_shr:1
        a = dpp_fmax<0x112>(a);   // row_shr:2
        a = dpp_fmax<0x114>(a);   // row_shr:4
        a = dpp_fmax<0x118>(a);   // row_shr:8  -> lane 15/31/47/63 = row max
        a = dpp_fmax<0x142>(a);   // row_bcast:15
        a = dpp_fmax<0x143>(a);   // row_bcast:31 -> lane 63 = wave max
        const float wmax =
            __int_as_float(__builtin_amdgcn_readlane(__float_as_int(a), 63));

        // winner lane = lowest lane holding wmax (== lowest global index)
        const unsigned long long m = __ballot(sb == wmax);
        const int wl   = __ffsll((long long)m) - 1;
        const int widx = __builtin_amdgcn_readlane(bi, wl);

        // --- one u64 key per wave: (score_bits+1)<<32 | (N-1-idx); 0 = empty.
        // +1 keeps monotone order and distinguishes active score 0.0 from empty;
        // low field breaks score ties toward the LOWEST index (matches argmax).
        if (lane == 0) {
            unsigned long long key = 0ULL;
            if (wmax >= 0.0f)
                key = ((((unsigned long long)__float_as_uint(wmax)) + 1ULL) << 32)
                    | (unsigned)(N - 1 - widx);
            redk[it & 1][wid] = key;
        }
        __syncthreads();   // double buffer -> one barrier per iteration is safe

        unsigned long long best = redk[it & 1][0];
        #pragma unroll
        for (int w = 1; w < NW; ++w) {
            const unsigned long long k = redk[it & 1][w];
            if (k > best) best = k;
        }
        if (best == 0ULL) break;   // all inactive; remaining ref steps are no-ops

        const int   i = (N - 1) - (int)(best & 0xFFFFu);
        const float v = __uint_as_float((unsigned)((best >> 32) - 1ULL));
        const float4 bb = sbox[i];       // broadcast ds_read_b128
        const float  ba = sar[i];

        #pragma unroll
        for (int e = 0; e < EPT; ++e) {
            const int j = base + e;
            const float xx1 = fmaxf(bb.x, x1[e]);
            const float yy1 = fmaxf(bb.y, y1[e]);
            const float xx2 = fminf(bb.z, x2[e]);
            const float yy2 = fminf(bb.w, y2[e]);
            const float ww  = fmaxf(xx2 - xx1 + 1.0f, 0.0f);
            const float hh  = fmaxf(yy2 - yy1 + 1.0f, 0.0f);
            const float inter = ww * hh;
            const float iou   = inter / (ba + ar[e] - inter);   // IEEE div (bit-exact)
            const float wgt   = expf(-(iou * iou) * 2.0f);      // libm (bit-exact)
            const bool  isI   = (j == i);
            const bool  act   = (s[e] >= 0.0f);
            const float ns    = act ? s[e] * wgt : s[e];
            fin[e] = isI ? v     : fin[e];
            s[e]   = isI ? -1.0f : ns;
        }
    }

    // --- outputs: final (B,N) f32 then keep (B,N) as 0/1 f32 ---
    float* of = out + (size_t)b * N;
    float* ok = out + (size_t)B * N + (size_t)b * N;
    #pragma unroll
    for (int e = 0; e < EPT; ++e) {
        const int j = base + e;
        of[j] = fin[e];
        ok[j] = (fin[e] > kThresh) ? 1.0f : 0.0f;
    }
}

extern "C" void kernel_launch(void* const* d_in, const int* in_sizes, int n_in,
                              void* d_out, int out_size, void* d_ws, size_t ws_size,
                              hipStream_t stream) {
    const float* det = (const float*)d_in[0];
    float* out = (float*)d_out;
    const int B = in_sizes[0] / (N * 5);
    hipLaunchKernelGGL(soft_nms_kernel, dim3(B), dim3(NT), 0, stream, det, out, B);
}

// Round 3
// 1554.104 us; speedup vs baseline: 1.4006x; 1.1743x over previous
//
#include <hip/hip_runtime.h>
#include <stdint.h>

static constexpr float kThresh = 0.3f;
static constexpr int N   = 2048;     // detections per batch (fixed by problem)
static constexpr int NT  = 256;      // threads per block (4 waves)
static constexpr int LPT = N / NT;   // 8 elements loaded/output per thread
static constexpr int E   = 8;        // max active slots per thread
static constexpr int NW  = NT / 64;  // 4 waves

using u64 = unsigned long long;

// One DPP u64-max step applied to both 32-bit halves (halves move identically,
// so the recombined pair is a coherent lane value; bound_ctrl=false + old=self
// makes invalid-source lanes a no-op). Validated sequence from round 2.
template <int CTRL>
__device__ __forceinline__ u64 dpp_max_u64_step(u64 k) {
    const int lo  = (int)(unsigned)k;
    const int hi  = (int)(unsigned)(k >> 32);
    const int mlo = __builtin_amdgcn_update_dpp(lo, lo, CTRL, 0xF, 0xF, false);
    const int mhi = __builtin_amdgcn_update_dpp(hi, hi, CTRL, 0xF, 0xF, false);
    const u64 m   = ((u64)(unsigned)mhi << 32) | (unsigned)mlo;
    return (m > k) ? m : k;
}

__device__ __forceinline__ u64 wave_max_u64(u64 k) {
    k = dpp_max_u64_step<0x111>(k);   // row_shr:1
    k = dpp_max_u64_step<0x112>(k);   // row_shr:2
    k = dpp_max_u64_step<0x114>(k);   // row_shr:4
    k = dpp_max_u64_step<0x118>(k);   // row_shr:8
    k = dpp_max_u64_step<0x142>(k);   // row_bcast:15
    k = dpp_max_u64_step<0x143>(k);   // row_bcast:31 -> lane 63 = wave max
    const int lo = __builtin_amdgcn_readlane((int)(unsigned)k, 63);
    const int hi = __builtin_amdgcn_readlane((int)(unsigned)(k >> 32), 63);
    return ((u64)(unsigned)hi << 32) | (unsigned)lo;
}

// key: (s_bits+1)<<32 | (2047-j)<<11 | pos.  s>=0 => monotone; +1 makes any
// active element beat the empty key 0; equal scores -> larger (2047-j) wins
// = LOWEST original index (exactly jnp.argmax); j unique so pos bits are free.
__device__ __forceinline__ u64 make_key(float s, int j, int pos) {
    return (((u64)(__float_as_uint(s) + 1u)) << 32)
         | (u64)(unsigned)(((N - 1 - j) << 11) | pos);
}

__launch_bounds__(NT, 1)
__global__ void soft_nms_kernel(const float* __restrict__ det,
                                float* __restrict__ out, int B) {
    const int b    = blockIdx.x;
    const int t    = threadIdx.x;
    const int lane = t & 63;
    const int wid  = t >> 6;

    __shared__ float4 sbox[N];     // static after prologue
    __shared__ float  sarea[N];    // static after prologue
    __shared__ float  sscore[N];   // initial scores (prologue reads only)
    __shared__ int    slist[N];    // active list (swap-remove)
    __shared__ float  sfin[N];     // recorded picked values
    __shared__ u64    redk[2][NW]; // double-buffered wave argmax keys
    __shared__ int    swave[NW];   // prefix-sum wave totals
    __shared__ float  sjit[2];     // double-buffered "last slot" decayed score

    const float* dbase = det + (size_t)b * N * 5;

    // ---------------- prologue: load, classify, compact ----------------
    int lval = 0, c = 0;
    #pragma unroll
    for (int e = 0; e < LPT; ++e) {
        const int j = t * LPT + e;
        const float* p = dbase + (size_t)j * 5;
        const float x1 = p[0], y1 = p[1], x2 = p[2], y2 = p[3], sc = p[4];
        sbox[j]   = make_float4(x1, y1, x2, y2);
        sarea[j]  = (x2 - x1 + 1.0f) * (y2 - y1 + 1.0f);
        sscore[j] = sc;
        sfin[j]   = -1.0f;
        const int va = sc > kThresh;
        lval |= va << e;
        c += va;
    }
    // wave-inclusive prefix of per-thread valid counts
    int pfx = c;
    #pragma unroll
    for (int d = 1; d < 64; d <<= 1) {
        const int v = __shfl_up(pfx, d, 64);
        if (lane >= d) pfx += v;
    }
    const int wtot = __builtin_amdgcn_readlane(pfx, 63);
    if (lane == 0) swave[wid] = wtot;
    __syncthreads();                                   // P1

    int wbase = 0, n0 = 0;
    #pragma unroll
    for (int w = 0; w < NW; ++w) {
        const int v = swave[w];
        if (w < wid) wbase += v;
        n0 += v;
    }
    int mypos = wbase + (pfx - c);                     // exclusive global prefix
    #pragma unroll
    for (int e = 0; e < LPT; ++e)
        if ((lval >> e) & 1) slist[mypos++] = t * LPT + e;
    __syncthreads();                                   // P2

    // ---- register-cached slots: thread t owns positions t, t+NT, ... ----
    int   jr[E]; float sr[E];
    float bx1[E], by1[E], bx2[E], by2[E], bar[E];
    u64 kk = 0;
    #pragma unroll
    for (int e = 0; e < E; ++e) {
        jr[e] = 0; sr[e] = 0.0f;
        bx1[e] = by1[e] = bx2[e] = by2[e] = bar[e] = 0.0f;
        const int pos = t + NT * e;
        if (pos < n0) {
            const int j = slist[pos];
            jr[e] = j; sr[e] = sscore[j];
            const float4 bb = sbox[j];
            bx1[e] = bb.x; by1[e] = bb.y; bx2[e] = bb.z; by2[e] = bb.w;
            bar[e] = sarea[j];
            const u64 key = make_key(sr[e], j, pos);
            if (key > kk) kk = key;
        }
    }
    kk = wave_max_u64(kk);
    if (lane == 0) redk[1][wid] = kk;                  // prologue uses parity 1
    __syncthreads();                                   // P3

    u64 best = redk[1][0];
    #pragma unroll
    for (int w = 1; w < NW; ++w) { const u64 o = redk[1][w]; if (o > best) best = o; }

    int    m = n0;                 // current active-list size
    int    prevPos = -1, prevLastJ = 0;
    float  prevLastS = 0.0f;
    float4 pb = make_float4(0.f, 0.f, 0.f, 0.f);
    float  pa = 0.0f;

    if (best != 0ULL) {            // first pick (no decay before it)
        const int   low  = (int)(unsigned)best;
        const int   posB = low & 0x7FF;
        const int   i    = (N - 1) - ((low >> 11) & 0x7FF);
        const float v    = __uint_as_float((unsigned)(best >> 32) - 1u);
        if (t == 0) sfin[i] = v;
        const int   lastJ = slist[m - 1];              // broadcast read
        const float lastS = sscore[lastJ];
        if (t == 0) slist[posB] = lastJ;               // swap-remove
        prevPos = posB; prevLastJ = lastJ; prevLastS = lastS;
        pb = sbox[i]; pa = sarea[i];
        m = n0 - 1;
    }

    // ---------------- main loop: one pass = decay-by-pick + next argmax ----
    int k = 0;
    while (m > 0) {
        const int par = k & 1;
        u64 kk2 = 0;
        #pragma unroll
        for (int e = 0; e < E; ++e) {
            const int pos = t + NT * e;
            if (pos < m) {
                if (pos == prevPos) {                  // element moved in by swap
                    const int j = prevLastJ;
                    jr[e] = j; sr[e] = prevLastS;
                    const float4 bb = sbox[j];
                    bx1[e] = bb.x; by1[e] = bb.y; bx2[e] = bb.z; by2[e] = bb.w;
                    bar[e] = sarea[j];
                }
                // byte-identical decay math (validated absmax==0 in r1/r2)
                const float xx1 = fmaxf(pb.x, bx1[e]);
                const float yy1 = fmaxf(pb.y, by1[e]);
                const float xx2 = fminf(pb.z, bx2[e]);
                const float yy2 = fminf(pb.w, by2[e]);
                const float ww  = fmaxf(xx2 - xx1 + 1.0f, 0.0f);
                const float hh  = fmaxf(yy2 - yy1 + 1.0f, 0.0f);
                const float inter = ww * hh;
                const float iou   = inter / (pa + bar[e] - inter);
                sr[e] *= expf(-(iou * iou) * 2.0f);    // *2 == /SIGMA(0.5) exactly
                if (pos == m - 1) sjit[par] = sr[e];   // JIT: next pass's moved score
                const u64 key = make_key(sr[e], jr[e], pos);
                if (key > kk2) kk2 = key;
            }
        }
        kk2 = wave_max_u64(kk2);
        if (lane == 0) redk[par][wid] = kk2;
        __syncthreads();                               // the one barrier / pass

        const int   lastJ = slist[m - 1];              // independent of best: issue early
        const float lastS = sjit[par];
        u64 bb2 = redk[par][0];
        #pragma unroll
        for (int w = 1; w < NW; ++w) { const u64 o = redk[par][w]; if (o > bb2) bb2 = o; }
        const int   low  = (int)(unsigned)bb2;         // m>0 => bb2 != 0
        const int   posB = low & 0x7FF;
        const int   i    = (N - 1) - ((low >> 11) & 0x7FF);
        const float v    = __uint_as_float((unsigned)(bb2 >> 32) - 1u);
        if (t == 0) { sfin[i] = v; slist[posB] = lastJ; }
        prevPos = posB; prevLastJ = lastJ; prevLastS = lastS;
        pb = sbox[i]; pa = sarea[i];
        --m; ++k;
    }

    __syncthreads();
    // outputs: final (B,N) f32 then keep (B,N) as 0/1 f32
    float* of = out + (size_t)b * N;
    float* ok = out + (size_t)B * N + (size_t)b * N;
    #pragma unroll
    for (int e = 0; e < LPT; ++e) {
        const int j = t * LPT + e;
        const float f = sfin[j];
        of[j] = f;
        ok[j] = (f > kThresh) ? 1.0f : 0.0f;
    }
}

extern "C" void kernel_launch(void* const* d_in, const int* in_sizes, int n_in,
                              void* d_out, int out_size, void* d_ws, size_t ws_size,
                              hipStream_t stream) {
    const float* det = (const float*)d_in[0];
    float* out = (float*)d_out;
    const int B = in_sizes[0] / (N * 5);
    hipLaunchKernelGGL(soft_nms_kernel, dim3(B), dim3(NT), 0, stream, det, out, B);
}